// Round 10
// baseline (151.036 us; speedup 1.0000x reference)
//
#include <hip/hip_runtime.h>
#include <math.h>

#define S_LEN 2048
#define EMB   1024
#define NHEAD 8
#define DH    128
#define E3    3072
#define BM    64      // Q rows per workgroup (16 per wave)
#define BN    32      // K tile
#define NSPLIT 4      // R22: revert (6 was a measured net loss in R21)
#define KSPLIT 8              // K-splits for the gate GEMM
#define KCH   (E3 / KSPLIT)   // 384 K per split
#define NGEMM (32 * KSPLIT)   // 256 gemm blocks
#define PTSTRIDE 40    // P LDS row stride: 80B rows, b128-aligned

typedef __bf16 bf16x8 __attribute__((ext_vector_type(8)));
typedef __bf16 bf16x4 __attribute__((ext_vector_type(4)));
typedef float  f32x4  __attribute__((ext_vector_type(4)));

// async 16B global->LDS (DMA path; counted by vmcnt, drained by __syncthreads)
__device__ __forceinline__ void gload16(const __bf16* g, __bf16* l) {
    __builtin_amdgcn_global_load_lds(
        (const __attribute__((address_space(1))) void*)g,
        (__attribute__((address_space(3))) void*)l, 16, 0, 0);
}

// ---------------------------------------------------------------------------
// Kernel 1 (R21 form, unchanged): gate GEMM (MFMA split-K) + K hi-lo cvt +
// V transpose, one dispatch.
// ---------------------------------------------------------------------------
__global__ __launch_bounds__(256) void gates_gemm_cvt_trans_kernel(
    const float* __restrict__ q, const float* __restrict__ k,
    const float* __restrict__ v,
    const float* __restrict__ Wi, const float* __restrict__ Wf,
    __bf16* __restrict__ Kh, __bf16* __restrict__ Kl,
    __bf16* __restrict__ Vt, float* __restrict__ gpart)
{
    const int tid = threadIdx.x;
    const int bid = blockIdx.x;
    __shared__ __bf16 tile[32][33];

    if (bid < NGEMM) {
        const int tt = bid >> 3, ks = bid & (KSPLIT - 1);
        const int w = tid >> 6, lane = tid & 63;
        const int quad = lane >> 4, l15 = lane & 15;
        const int tbase = tt * 64 + w * 16;
        const float* wrow = (l15 < 8) ? (Wi + l15 * E3) : (Wf + (l15 - 8) * E3);
        f32x4 acc = {0.f, 0.f, 0.f, 0.f};
        #pragma unroll
        for (int j = 0; j < KCH / 32; ++j) {
            const int K0 = ks * KCH + j * 32;
            const float* src; int off;
            if (K0 < 1024)      { src = q; off = K0; }
            else if (K0 < 2048) { src = k; off = K0 - 1024; }
            else                { src = v; off = K0 - 2048; }
            const float* ap = src + (size_t)(tbase + l15) * EMB + off + quad * 8;
            float4 a0 = *(const float4*)ap,       a1 = *(const float4*)(ap + 4);
            const float* bp = wrow + K0 + quad * 8;
            float4 b0 = *(const float4*)bp,       b1 = *(const float4*)(bp + 4);
            float af[8] = {a0.x,a0.y,a0.z,a0.w,a1.x,a1.y,a1.z,a1.w};
            float bfv[8] = {b0.x,b0.y,b0.z,b0.w,b1.x,b1.y,b1.z,b1.w};
            bf16x8 ah, al, bh, bl;
            #pragma unroll
            for (int e = 0; e < 8; ++e) {
                __bf16 ha = (__bf16)af[e];
                ah[e] = ha; al[e] = (__bf16)(af[e] - (float)ha);
                __bf16 hb = (__bf16)bfv[e];
                bh[e] = hb; bl[e] = (__bf16)(bfv[e] - (float)hb);
            }
            acc = __builtin_amdgcn_mfma_f32_16x16x32_bf16(ah, bh, acc, 0, 0, 0);
            acc = __builtin_amdgcn_mfma_f32_16x16x32_bf16(ah, bl, acc, 0, 0, 0);
            acc = __builtin_amdgcn_mfma_f32_16x16x32_bf16(al, bh, acc, 0, 0, 0);
        }
        float* gp = gpart + (size_t)(ks * 16 + l15) * S_LEN + tbase;
        #pragma unroll
        for (int r = 0; r < 4; ++r) gp[quad * 4 + r] = acc[r];
    } else if (bid < NGEMM + S_LEN) {
        const int t = bid - NGEMM;
        const float4 kv = ((const float4*)k)[(size_t)t * 256 + tid];
        size_t idx = (size_t)t * 256 + tid;
        bf16x4 hi, lo;
        hi[0]=(__bf16)kv.x; hi[1]=(__bf16)kv.y; hi[2]=(__bf16)kv.z; hi[3]=(__bf16)kv.w;
        lo[0]=(__bf16)(kv.x-(float)hi[0]); lo[1]=(__bf16)(kv.y-(float)hi[1]);
        lo[2]=(__bf16)(kv.z-(float)hi[2]); lo[3]=(__bf16)(kv.w-(float)hi[3]);
        ((bf16x4*)Kh)[idx] = hi; ((bf16x4*)Kl)[idx] = lo;
    } else {
        const int tb = bid - NGEMM - S_LEN;
        const int sb = (tb & 63) * 32, eb = (tb >> 6) * 32;
        #pragma unroll
        for (int i = 0; i < 4; ++i) {
            int lin = tid + i * 256;
            int sr = lin >> 5, ec = lin & 31;
            tile[ec][sr] = (__bf16)v[(size_t)(sb + sr) * EMB + eb + ec];
        }
        __syncthreads();
        #pragma unroll
        for (int i = 0; i < 4; ++i) {
            int lin = tid + i * 256;
            int er = lin >> 5, sc = lin & 31;
            Vt[(size_t)(eb + er) * S_LEN + sb + sc] = tile[er][sc];
        }
    }
}

// ---------------------------------------------------------------------------
// Kernel 2 (R20 form): combine gate partials + bias + log-sigmoid + scan.
// ---------------------------------------------------------------------------
__global__ __launch_bounds__(256) void cumsum_aux_kernel(
    const float* __restrict__ gpart,
    const float* __restrict__ bi, const float* __restrict__ bfp,
    float* __restrict__ F, float* __restrict__ ug,
    float* __restrict__ umax, float* __restrict__ upmax)
{
    const int h = blockIdx.x, tid = threadIdx.x;
    const int lane = tid & 63, w = tid >> 6;
    __shared__ float wsum[4];
    __shared__ float morig[256];
    const float bih = bi[h], bfh = bfp[h];
    float loc[8], igv[8];
    const int base = tid * 8;
    float s = 0.f;
    for (int i = 0; i < 8; i++) {
        const int t = base + i;
        float ri = 0.f, rf = 0.f;
        #pragma unroll
        for (int ks = 0; ks < KSPLIT; ++ks) {
            ri += gpart[(size_t)(ks * 16 + h) * S_LEN + t];
            rf += gpart[(size_t)(ks * 16 + 8 + h) * S_LEN + t];
        }
        igv[i] = ri + bih;
        float x = rf + bfh;
        float lfv = fminf(x, 0.f) - log1pf(expf(-fabsf(x)));
        s += lfv; loc[i] = s;
    }
    float inc = s;
    #pragma unroll
    for (int o = 1; o < 64; o <<= 1) {
        float t = __shfl_up(inc, o, 64);
        if (lane >= o) inc += t;
    }
    if (lane == 63) wsum[w] = inc;
    __syncthreads();
    float wpre = 0.f;
    #pragma unroll
    for (int i = 0; i < 4; ++i) if (i < w) wpre += wsum[i];
    const float prev = wpre + inc - s;
    float* Fh = F + h * (S_LEN + 1);
    if (tid == 0) Fh[0] = 0.f;
    float Fv[8];
    for (int i = 0; i < 8; i++) { Fv[i] = prev + loc[i]; Fh[base + i + 1] = Fv[i]; }

    float pm[8];
    float runm = -1e30f;
    #pragma unroll
    for (int i = 0; i < 8; i++) {
        float u = igv[i] - Fv[i];
        ug[h * S_LEN + base + i] = u;
        runm = fmaxf(runm, u);
        pm[i] = runm;
    }
    morig[tid] = runm;
    __syncthreads();
    const int g0 = tid & ~3;
    float pfx = -1e30f;
    for (int j = g0; j < tid; ++j) pfx = fmaxf(pfx, morig[j]);
    #pragma unroll
    for (int i = 0; i < 8; i++)
        upmax[h * S_LEN + base + i] = fmaxf(pfx, pm[i]);
    if ((tid & 3) == 0) {
        float mm = fmaxf(fmaxf(morig[tid], morig[tid + 1]),
                         fmaxf(morig[tid + 2], morig[tid + 3]));
        umax[h * 64 + (tid >> 2)] = mm;
    }
}

// ---------------------------------------------------------------------------
// Kernel 3: flash mLSTM. R22: exact minimum-2-phase pipeline (catalog T3):
//   * K AND V both double-buffered; ALL 6 next-tile loads issued at loop-TOP;
//   * compute the whole tile (QK^T + softmax + PV) from current buffers;
//   * ONE __syncthreads() per iteration at the bottom -- its vmcnt(0) drain is
//     semantically required there (next iter reads the staged data), and the
//     loads had the entire tile's compute in flight. R18's structure paid two
//     full drains/iter and staged V with zero latency window -- the prefetch
//     never survived a barrier (the m97 stall).
// NSPLIT=4 (R21's 6 was a net loss). Q fp32-direct cvt kept (R21, overlapped
// with first-tile DMA). Grid 512 paired {x,31-x}.
// ---------------------------------------------------------------------------
__global__ __launch_bounds__(256, 2) void mlstm_mfma(
    const float* __restrict__ Qg,
    const __bf16* __restrict__ Khg, const __bf16* __restrict__ Klg,
    const __bf16* __restrict__ Vtg,
    const float* __restrict__ ug, const float* __restrict__ umaxg,
    const float* __restrict__ upmaxg, const float* __restrict__ F,
    __bf16* __restrict__ Opart, float* __restrict__ msplit,
    float* __restrict__ lsplit)
{
    const int flat = blockIdx.x;
    const int h = flat & 7;
    const int rest = flat >> 3;
    const int xx = rest & 15, z = rest >> 4;   // z in [0,4)
    const int tid  = threadIdx.x;
    const int lane = tid & 63, w = tid >> 6;
    const int quad = lane >> 4, l15 = lane & 15;

    __shared__ __bf16 KhL[2][4096];     // 32 rows x 128 bf16, linear, dbuf
    __shared__ __bf16 KlL[2][4096];
    __shared__ __bf16 VtL[2][4096];     // 128 rows x 32 bf16, dbuf (R22)
    __shared__ __bf16 Pt[4][16 * PTSTRIDE];

    const float* Fh  = F  + h * (S_LEN + 1);
    const float* ugh = ug + h * S_LEN;
    const float scale = 0.088388347648318447f; // 1/sqrt(128)

    const int krow0 = tid >> 4;
    const int krow1 = 16 + krow0;
    const int kchk  = (tid & 15) ^ (krow0 & 15);
    const int vrow0 = tid >> 2;
    const int vrow1 = 64 + vrow0;
    const int vchk  = (tid & 3) ^ ((vrow0 ^ (vrow0 >> 2)) & 3);
    const int ldsw  = w * 512;

#define STAGE(B, TB) do {                                                     \
    const __bf16* kb_ = Khg + (size_t)(TB) * EMB + h * DH;                    \
    const __bf16* lb_ = Klg + (size_t)(TB) * EMB + h * DH;                    \
    const __bf16* vg_ = Vtg + (size_t)(h * DH) * S_LEN + (TB);                \
    gload16(kb_ + (size_t)krow0 * EMB + kchk * 8, &KhL[B][ldsw]);             \
    gload16(kb_ + (size_t)krow1 * EMB + kchk * 8, &KhL[B][2048 + ldsw]);      \
    gload16(lb_ + (size_t)krow0 * EMB + kchk * 8, &KlL[B][ldsw]);             \
    gload16(lb_ + (size_t)krow1 * EMB + kchk * 8, &KlL[B][2048 + ldsw]);      \
    gload16(vg_ + (size_t)vrow0 * S_LEN + vchk * 8, &VtL[B][ldsw]);           \
    gload16(vg_ + (size_t)vrow1 * S_LEN + vchk * 8, &VtL[B][2048 + ldsw]);    \
} while (0)

    for (int pair = 0; pair < 2; ++pair) {
        const int qt = (pair == 0) ? xx : 31 - xx;
        const int qb = qt * BM;
        const int nj = 2 * qt + 2;
        const int j0 = (z * nj) / NSPLIT, j1 = ((z + 1) * nj) / NSPLIT;
        const int qbw = qb + w * 16;
        const int SBLK = (qb >> 5) + (w >> 1);   // uniform per wave

        float fq[4], upm[4];
        int sglob[4];
        #pragma unroll
        for (int r = 0; r < 4; ++r) {
            int s = qbw + quad * 4 + r;
            sglob[r] = s;
            fq[r]  = Fh[s + 1];
            upm[r] = upmaxg[h * S_LEN + s];
        }

        float pu0 = 0.f, pu1 = 0.f, pum = 0.f;
        int buf = 0;
        if (j0 < j1) {               // issue first tile DMA before Q cvt
            STAGE(0, j0 * BN);
            pu0 = ugh[j0 * BN + l15];
            pu1 = ugh[j0 * BN + 16 + l15];
            pum = umaxg[h * 64 + j0];
        }

        // ---- Q fp32 -> hi/lo bf16 frags, in-register (overlaps first DMA) ----
        bf16x8 qh[4], ql[4];
        {
            const float* qp = Qg + (size_t)(qbw + l15) * EMB + h * DH + quad * 8;
            #pragma unroll
            for (int kk = 0; kk < 4; ++kk) {
                float4 a = *(const float4*)(qp + kk * 32);
                float4 b = *(const float4*)(qp + kk * 32 + 4);
                float f[8] = {a.x, a.y, a.z, a.w, b.x, b.y, b.z, b.w};
                #pragma unroll
                for (int e = 0; e < 8; ++e) {
                    __bf16 hi = (__bf16)f[e];
                    qh[kk][e] = hi;
                    ql[kk][e] = (__bf16)(f[e] - (float)hi);
                }
            }
        }
        #pragma unroll
        for (int kk = 0; kk < 4; ++kk)
            asm volatile("" : "+v"(qh[kk]), "+v"(ql[kk]));

        float m_r[4] = {-1e30f, -1e30f, -1e30f, -1e30f};
        float l_r[4] = {0.f, 0.f, 0.f, 0.f};
        f32x4 Oacc[8] = {{0,0,0,0},{0,0,0,0},{0,0,0,0},{0,0,0,0},
                         {0,0,0,0},{0,0,0,0},{0,0,0,0},{0,0,0,0}};

        if (j0 < j1) __syncthreads();   // first tile landed (block-uniform cond)

        for (int j = j0; j < j1; ++j) {
            const int tb = j * BN;
            const float ut0 = pu0, ut1 = pu1, umj = pum;
            if (j + 1 < j1) {   // ALL next-tile loads at top: full-tile window
                STAGE(buf ^ 1, tb + BN);
                pu0 = ugh[tb + BN + l15];
                pu1 = ugh[tb + BN + 16 + l15];
                pum = umaxg[h * 64 + (j + 1)];
            }
            if (j <= SBLK) {   // wave-uniform: skip fully-masked tiles
                // ---- S = Q K^T (split-bf16), both t-halves per wave ----
                f32x4 S0 = {0,0,0,0}, S1 = {0,0,0,0};
                #pragma unroll
                for (int kk = 0; kk < 4; ++kk) {
                    const int kpos = (((kk << 2) | quad) ^ l15) * 8;
                    bf16x8 bh0 = *(const bf16x8*)&KhL[buf][l15 * 128 + kpos];
                    bf16x8 bl0 = *(const bf16x8*)&KlL[buf][l15 * 128 + kpos];
                    S0 = __builtin_amdgcn_mfma_f32_16x16x32_bf16(qh[kk], bh0, S0, 0, 0, 0);
                    S0 = __builtin_amdgcn_mfma_f32_16x16x32_bf16(qh[kk], bl0, S0, 0, 0, 0);
                    S0 = __builtin_amdgcn_mfma_f32_16x16x32_bf16(ql[kk], bh0, S0, 0, 0, 0);
                    bf16x8 bh1 = *(const bf16x8*)&KhL[buf][(16 + l15) * 128 + kpos];
                    bf16x8 bl1 = *(const bf16x8*)&KlL[buf][(16 + l15) * 128 + kpos];
                    S1 = __builtin_amdgcn_mfma_f32_16x16x32_bf16(qh[kk], bh1, S1, 0, 0, 0);
                    S1 = __builtin_amdgcn_mfma_f32_16x16x32_bf16(qh[kk], bl1, S1, 0, 0, 0);
                    S1 = __builtin_amdgcn_mfma_f32_16x16x32_bf16(ql[kk], bh1, S1, 0, 0, 0);
                }
                // ---- gates + online softmax, deferred l-reduce ----
                const int t0 = tb + l15, t1 = tb + 16 + l15;
                #pragma unroll
                for (int r = 0; r < 4; ++r) {
                    float mt = (j < SBLK) ? (fq[r] + umj) : (fq[r] + upm[r]);
                    float mn = fmaxf(m_r[r], mt);
                    float alpha = __expf(m_r[r] - mn);
                    m_r[r] = mn;
                    #pragma unroll
                    for (int nt = 0; nt < 8; ++nt) Oacc[nt][r] *= alpha;
                    float p0 = __expf(fq[r] + ut0 - mn) * S0[r] * scale;
                    float p1 = __expf(fq[r] + ut1 - mn) * S1[r] * scale;
                    if (j == SBLK) {
                        if (t0 > sglob[r]) p0 = 0.f;
                        if (t1 > sglob[r]) p1 = 0.f;
                    }
                    l_r[r] = l_r[r] * alpha + (p0 + p1);  // per-lane partial
                    const int prow = (quad * 4 + r) * PTSTRIDE;
                    Pt[w][prow + l15]      = (__bf16)p0;
                    Pt[w][prow + 16 + l15] = (__bf16)p1;
                }
                // ---- O += P V (P wave-private; V from current buffer) ----
                bf16x8 pa = *(const bf16x8*)&Pt[w][l15 * PTSTRIDE + quad * 8];
                #pragma unroll
                for (int nt = 0; nt < 8; ++nt) {
                    const int vrow = nt * 16 + l15;
                    const int vpos = (quad ^ ((vrow ^ (vrow >> 2)) & 3)) * 8;
                    bf16x8 vv = *(const bf16x8*)&VtL[buf][vrow * 32 + vpos];
                    Oacc[nt] = __builtin_amdgcn_mfma_f32_16x16x32_bf16(pa, vv, Oacc[nt], 0, 0, 0);
                }
            }
            __syncthreads();   // ONE barrier/iter: next tile landed + buf free
            buf ^= 1;
        }
        // ---- epilogue ----
        const bool active = (j0 < j1) && (j0 <= SBLK);  // wave-uniform
        if (active) {
            __bf16* Oz = Opart + (size_t)z * S_LEN * EMB;
            #pragma unroll
            for (int nt = 0; nt < 8; ++nt) {
                #pragma unroll
                for (int r = 0; r < 4; ++r) {
                    Oz[(size_t)sglob[r] * EMB + h * DH + nt * 16 + l15] = (__bf16)Oacc[nt][r];
                }
            }
        }
        #pragma unroll
        for (int r = 0; r < 4; ++r) {
            float x = l_r[r];
            #pragma unroll
            for (int o = 1; o < 16; o <<= 1) x += __shfl_xor(x, o);
            l_r[r] = x;
        }
        if (l15 == 0) {
            #pragma unroll
            for (int r = 0; r < 4; ++r) {
                msplit[(z * NHEAD + h) * S_LEN + sglob[r]] = m_r[r];
                lsplit[(z * NHEAD + h) * S_LEN + sglob[r]] = l_r[r];
            }
        }
    }
#undef STAGE
}

// ---------------------------------------------------------------------------
// Kernel 4: combine split-K partials + normalize + LN (NSPLIT=4, es!=0 skip).
// ---------------------------------------------------------------------------
__global__ __launch_bounds__(256) void combine_ln_kernel(
    const __bf16* __restrict__ Opart, const float* __restrict__ msplit,
    const float* __restrict__ lsplit, const float* __restrict__ lnw,
    float* __restrict__ out)
{
    const int tid = threadIdx.x;
    const int r  = tid >> 7;          // row within block (0/1)
    const int wr = (tid >> 6) & 1;    // wave within row
    const int c0 = (tid & 127) * 8;   // 8 contiguous cols per thread
    const int hh = c0 >> 7;
    const int s  = blockIdx.x * 2 + r;
    __shared__ float redsum[2][2], redvar[2][2];

    float m = -1e30f, es[NSPLIT], l = 0.f;
    #pragma unroll
    for (int zz = 0; zz < NSPLIT; ++zz)
        m = fmaxf(m, msplit[(zz * NHEAD + hh) * S_LEN + s]);
    #pragma unroll
    for (int zz = 0; zz < NSPLIT; ++zz) {
        es[zz] = __expf(msplit[(zz * NHEAD + hh) * S_LEN + s] - m);
        l += es[zz] * lsplit[(zz * NHEAD + hh) * S_LEN + s];
    }
    const float rn = 1.f / (fmaxf(fabsf(l), __expf(-m)) + 1e-6f);

    const size_t SE = (size_t)S_LEN * EMB;
    float x[8] = {0,0,0,0,0,0,0,0};
    #pragma unroll
    for (int zz = 0; zz < NSPLIT; ++zz) {
        if (es[zz] != 0.f) {
            bf16x8 o = *(const bf16x8*)(Opart + zz * SE + (size_t)s * EMB + c0);
            #pragma unroll
            for (int e = 0; e < 8; ++e) x[e] += es[zz] * (float)o[e];
        }
    }
    float sum = 0.f;
    #pragma unroll
    for (int e = 0; e < 8; ++e) { x[e] *= rn; sum += x[e]; }
    for (int o = 32; o > 0; o >>= 1) sum += __shfl_down(sum, o, 64);
    if ((tid & 63) == 0) redsum[r][wr] = sum;
    __syncthreads();
    sum = redsum[r][0] + redsum[r][1];
    const float mu = sum * (1.f / EMB);
    float vs = 0.f;
    #pragma unroll
    for (int e = 0; e < 8; ++e) { float d = x[e] - mu; vs += d * d; }
    for (int o = 32; o > 0; o >>= 1) vs += __shfl_down(vs, o, 64);
    if ((tid & 63) == 0) redvar[r][wr] = vs;
    __syncthreads();
    vs = redvar[r][0] + redvar[r][1];
    const float rstd = rsqrtf(vs * (1.f / EMB) + 1e-5f);
    const float4 w0 = *(const float4*)(lnw + c0);
    const float4 w1 = *(const float4*)(lnw + c0 + 4);
    float4 o0, o1;
    o0.x = (x[0]-mu)*rstd*(1.f+w0.x); o0.y = (x[1]-mu)*rstd*(1.f+w0.y);
    o0.z = (x[2]-mu)*rstd*(1.f+w0.z); o0.w = (x[3]-mu)*rstd*(1.f+w0.w);
    o1.x = (x[4]-mu)*rstd*(1.f+w1.x); o1.y = (x[5]-mu)*rstd*(1.f+w1.y);
    o1.z = (x[6]-mu)*rstd*(1.f+w1.z); o1.w = (x[7]-mu)*rstd*(1.f+w1.w);
    *(float4*)(out + (size_t)s * EMB + c0)     = o0;
    *(float4*)(out + (size_t)s * EMB + c0 + 4) = o1;
}

// ---------------------------------------------------------------------------
extern "C" void kernel_launch(void* const* d_in, const int* in_sizes, int n_in,
                              void* d_out, int out_size, void* d_ws, size_t ws_size,
                              hipStream_t stream)
{
    const float* q   = (const float*)d_in[0];
    const float* k   = (const float*)d_in[1];
    const float* v   = (const float*)d_in[2];
    const float* Wi  = (const float*)d_in[3];
    const float* bi  = (const float*)d_in[4];
    const float* Wf  = (const float*)d_in[5];
    const float* bf  = (const float*)d_in[6];
    const float* lnw = (const float*)d_in[7];
    float* out = (float*)d_out;

    // workspace layout (~30 MB; 38.6 proven safe):
    float* ws = (float*)d_ws;
    float* gpart = ws;                              // KSPLIT*16*S (1 MB)
    float* F     = gpart + KSPLIT * 16 * S_LEN;     // NH*(S+1)
    float* ugw   = F + NHEAD * (S_LEN + 1);         // NH*S
    float* umaxw = ugw + NHEAD * S_LEN;             // NH*64
    float* upmaxw= umaxw + NHEAD * 64;              // NH*S
    __bf16* Kh = (__bf16*)(upmaxw + NHEAD * S_LEN);
    const size_t SEb = (size_t)S_LEN * EMB;
    __bf16* Kl  = Kh + SEb;
    __bf16* Vtg = Kl + SEb;
    __bf16* Opart = Vtg + SEb;                      // NSPLIT*S*EMB bf16 (16 MB)
    float* msplit = (float*)(Opart + (size_t)NSPLIT * SEb);
    float* lsplit = msplit + NSPLIT * NHEAD * S_LEN;

    gates_gemm_cvt_trans_kernel<<<NGEMM + S_LEN + 2048, 256, 0, stream>>>(
        q, k, v, Wi, Wf, Kh, Kl, Vtg, gpart);
    cumsum_aux_kernel<<<NHEAD, 256, 0, stream>>>(
        gpart, bi, bf, F, ugw, umaxw, upmaxw);
    mlstm_mfma<<<16 * NHEAD * NSPLIT, 256, 0, stream>>>(
        q, Kh, Kl, Vtg, ugw, umaxw, upmaxw, F, Opart, msplit, lsplit);
    combine_ln_kernel<<<S_LEN / 2, 256, 0, stream>>>(Opart, msplit, lsplit, lnw, out);
}

// Round 11
// 147.251 us; speedup vs baseline: 1.0257x; 1.0257x over previous
//
#include <hip/hip_runtime.h>
#include <math.h>

#define S_LEN 2048
#define EMB   1024
#define NHEAD 8
#define DH    128
#define E3    3072
#define BM    64      // Q rows per workgroup (16 per wave)
#define BN    32      // K tile
#define NSPLIT 4
#define KSPLIT 8              // K-splits for the gate GEMM
#define KCH   (E3 / KSPLIT)   // 384 K per split
#define NGEMM (32 * KSPLIT)   // 256 gemm blocks
#define PTSTRIDE 40    // P LDS row stride: 80B rows, b128-aligned

typedef __bf16 bf16x8 __attribute__((ext_vector_type(8)));
typedef __bf16 bf16x4 __attribute__((ext_vector_type(4)));
typedef float  f32x4  __attribute__((ext_vector_type(4)));

// async 16B global->LDS (DMA path; counted by vmcnt, drained by __syncthreads)
__device__ __forceinline__ void gload16(const __bf16* g, __bf16* l) {
    __builtin_amdgcn_global_load_lds(
        (const __attribute__((address_space(1))) void*)g,
        (__attribute__((address_space(3))) void*)l, 16, 0, 0);
}

// ---------------------------------------------------------------------------
// Kernel 1 (R23 = R20 + vectorized vtrans I/O): three sections, one dispatch.
//  [0,256):          gate GEMM via MFMA split-K (R20-proven).
//  [256,2304):       q/k hi-lo cvt (R14-proven vectorized form, bit-identical)
//  [2304,4352):      V transpose; R23: float4 loads / bf16x4 stores (G13 —
//                    were scalar 4B/2B per lane). Same tile layout & values.
// ---------------------------------------------------------------------------
__global__ __launch_bounds__(256) void gates_gemm_cvt_trans_kernel(
    const float* __restrict__ q, const float* __restrict__ k,
    const float* __restrict__ v,
    const float* __restrict__ Wi, const float* __restrict__ Wf,
    __bf16* __restrict__ Qh, __bf16* __restrict__ Ql,
    __bf16* __restrict__ Kh, __bf16* __restrict__ Kl,
    __bf16* __restrict__ Vt, float* __restrict__ gpart)
{
    const int tid = threadIdx.x;
    const int bid = blockIdx.x;
    __shared__ __bf16 tile[32][33];

    if (bid < NGEMM) {
        // ---- gate GEMM: token-tile tt (64 tokens), K-split ks (384 K) ----
        const int tt = bid >> 3, ks = bid & (KSPLIT - 1);
        const int w = tid >> 6, lane = tid & 63;
        const int quad = lane >> 4, l15 = lane & 15;
        const int tbase = tt * 64 + w * 16;          // wave's 16 tokens
        const float* wrow = (l15 < 8) ? (Wi + l15 * E3) : (Wf + (l15 - 8) * E3);
        f32x4 acc = {0.f, 0.f, 0.f, 0.f};
        #pragma unroll
        for (int j = 0; j < KCH / 32; ++j) {
            const int K0 = ks * KCH + j * 32;
            const float* src; int off;
            if (K0 < 1024)      { src = q; off = K0; }
            else if (K0 < 2048) { src = k; off = K0 - 1024; }
            else                { src = v; off = K0 - 2048; }
            const float* ap = src + (size_t)(tbase + l15) * EMB + off + quad * 8;
            float4 a0 = *(const float4*)ap,       a1 = *(const float4*)(ap + 4);
            const float* bp = wrow + K0 + quad * 8;
            float4 b0 = *(const float4*)bp,       b1 = *(const float4*)(bp + 4);
            float af[8] = {a0.x,a0.y,a0.z,a0.w,a1.x,a1.y,a1.z,a1.w};
            float bfv[8] = {b0.x,b0.y,b0.z,b0.w,b1.x,b1.y,b1.z,b1.w};
            bf16x8 ah, al, bh, bl;
            #pragma unroll
            for (int e = 0; e < 8; ++e) {
                __bf16 ha = (__bf16)af[e];
                ah[e] = ha; al[e] = (__bf16)(af[e] - (float)ha);
                __bf16 hb = (__bf16)bfv[e];
                bh[e] = hb; bl[e] = (__bf16)(bfv[e] - (float)hb);
            }
            acc = __builtin_amdgcn_mfma_f32_16x16x32_bf16(ah, bh, acc, 0, 0, 0);
            acc = __builtin_amdgcn_mfma_f32_16x16x32_bf16(ah, bl, acc, 0, 0, 0);
            acc = __builtin_amdgcn_mfma_f32_16x16x32_bf16(al, bh, acc, 0, 0, 0);
        }
        // C layout (k3-verified): m = quad*4+r (token), n = l15 (gate)
        float* gp = gpart + (size_t)(ks * 16 + l15) * S_LEN + tbase;
        #pragma unroll
        for (int r = 0; r < 4; ++r) gp[quad * 4 + r] = acc[r];
    } else if (bid < NGEMM + S_LEN) {
        // ---- q/k hi-lo cvt (R14 form, bit-identical outputs) ----
        const int t = bid - NGEMM;
        const float4 qv = ((const float4*)q)[(size_t)t * 256 + tid];
        const float4 kv = ((const float4*)k)[(size_t)t * 256 + tid];
        size_t idx = (size_t)t * 256 + tid;
        bf16x4 hi, lo;
        hi[0]=(__bf16)qv.x; hi[1]=(__bf16)qv.y; hi[2]=(__bf16)qv.z; hi[3]=(__bf16)qv.w;
        lo[0]=(__bf16)(qv.x-(float)hi[0]); lo[1]=(__bf16)(qv.y-(float)hi[1]);
        lo[2]=(__bf16)(qv.z-(float)hi[2]); lo[3]=(__bf16)(qv.w-(float)hi[3]);
        ((bf16x4*)Qh)[idx] = hi; ((bf16x4*)Ql)[idx] = lo;
        hi[0]=(__bf16)kv.x; hi[1]=(__bf16)kv.y; hi[2]=(__bf16)kv.z; hi[3]=(__bf16)kv.w;
        lo[0]=(__bf16)(kv.x-(float)hi[0]); lo[1]=(__bf16)(kv.y-(float)hi[1]);
        lo[2]=(__bf16)(kv.z-(float)hi[2]); lo[3]=(__bf16)(kv.w-(float)hi[3]);
        ((bf16x4*)Kh)[idx] = hi; ((bf16x4*)Kl)[idx] = lo;
    } else {
        // ---- V transpose tiles, vectorized I/O (R23) ----
        const int tb = bid - NGEMM - S_LEN;
        const int sb = (tb & 63) * 32, eb = (tb >> 6) * 32;
        {
            const int sr = tid >> 3, e4 = (tid & 7) * 4;   // 32 rows x 8 groups
            float4 vv = *(const float4*)&v[(size_t)(sb + sr) * EMB + eb + e4];
            tile[e4 + 0][sr] = (__bf16)vv.x;
            tile[e4 + 1][sr] = (__bf16)vv.y;
            tile[e4 + 2][sr] = (__bf16)vv.z;
            tile[e4 + 3][sr] = (__bf16)vv.w;
        }
        __syncthreads();
        {
            const int er = tid >> 3, sc4 = (tid & 7) * 4;  // 32 rows x 8 groups
            bf16x4 o;
            o[0] = tile[er][sc4 + 0]; o[1] = tile[er][sc4 + 1];
            o[2] = tile[er][sc4 + 2]; o[3] = tile[er][sc4 + 3];
            *(bf16x4*)&Vt[(size_t)(eb + er) * S_LEN + sb + sc4] = o;
        }
    }
}

// ---------------------------------------------------------------------------
// Kernel 2 (R20 form): combine gate partials + bias + log-sigmoid + scan.
// ---------------------------------------------------------------------------
__global__ __launch_bounds__(256) void cumsum_aux_kernel(
    const float* __restrict__ gpart,
    const float* __restrict__ bi, const float* __restrict__ bfp,
    float* __restrict__ F, float* __restrict__ ug,
    float* __restrict__ umax, float* __restrict__ upmax)
{
    const int h = blockIdx.x, tid = threadIdx.x;
    const int lane = tid & 63, w = tid >> 6;
    __shared__ float wsum[4];
    __shared__ float morig[256];
    const float bih = bi[h], bfh = bfp[h];
    float loc[8], igv[8];
    const int base = tid * 8;
    float s = 0.f;
    for (int i = 0; i < 8; i++) {
        const int t = base + i;
        float ri = 0.f, rf = 0.f;
        #pragma unroll
        for (int ks = 0; ks < KSPLIT; ++ks) {
            ri += gpart[(size_t)(ks * 16 + h) * S_LEN + t];
            rf += gpart[(size_t)(ks * 16 + 8 + h) * S_LEN + t];
        }
        igv[i] = ri + bih;
        float x = rf + bfh;
        float lfv = fminf(x, 0.f) - log1pf(expf(-fabsf(x)));
        s += lfv; loc[i] = s;
    }
    float inc = s;
    #pragma unroll
    for (int o = 1; o < 64; o <<= 1) {
        float t = __shfl_up(inc, o, 64);
        if (lane >= o) inc += t;
    }
    if (lane == 63) wsum[w] = inc;
    __syncthreads();
    float wpre = 0.f;
    #pragma unroll
    for (int i = 0; i < 4; ++i) if (i < w) wpre += wsum[i];
    const float prev = wpre + inc - s;
    float* Fh = F + h * (S_LEN + 1);
    if (tid == 0) Fh[0] = 0.f;
    float Fv[8];
    for (int i = 0; i < 8; i++) { Fv[i] = prev + loc[i]; Fh[base + i + 1] = Fv[i]; }

    float pm[8];
    float runm = -1e30f;
    #pragma unroll
    for (int i = 0; i < 8; i++) {
        float u = igv[i] - Fv[i];
        ug[h * S_LEN + base + i] = u;
        runm = fmaxf(runm, u);
        pm[i] = runm;
    }
    morig[tid] = runm;
    __syncthreads();
    const int g0 = tid & ~3;
    float pfx = -1e30f;
    for (int j = g0; j < tid; ++j) pfx = fmaxf(pfx, morig[j]);
    #pragma unroll
    for (int i = 0; i < 8; i++)
        upmax[h * S_LEN + base + i] = fmaxf(pfx, pm[i]);
    if ((tid & 3) == 0) {
        float mm = fmaxf(fmaxf(morig[tid], morig[tid + 1]),
                         fmaxf(morig[tid + 2], morig[tid + 3]));
        umax[h * 64 + (tid >> 2)] = mm;
    }
}

// ---------------------------------------------------------------------------
// Kernel 3: flash mLSTM. R20/R18 version BYTE-FROZEN (best measured): V
// single-buffered, K dbuf, global_load_lds + rule-21 swizzle, two barriers,
// precomputed Qh/Ql frags with asm pin, grid 512 paired {x,31-x}.
// ---------------------------------------------------------------------------
__global__ __launch_bounds__(256, 2) void mlstm_mfma(
    const __bf16* __restrict__ Qhg, const __bf16* __restrict__ Qlg,
    const __bf16* __restrict__ Khg, const __bf16* __restrict__ Klg,
    const __bf16* __restrict__ Vtg,
    const float* __restrict__ ug, const float* __restrict__ umaxg,
    const float* __restrict__ upmaxg, const float* __restrict__ F,
    __bf16* __restrict__ Opart, float* __restrict__ msplit,
    float* __restrict__ lsplit)
{
    const int flat = blockIdx.x;
    const int h = flat & 7;
    const int rest = flat >> 3;
    const int xx = rest & 15, z = rest >> 4;
    const int tid  = threadIdx.x;
    const int lane = tid & 63, w = tid >> 6;
    const int quad = lane >> 4, l15 = lane & 15;

    __shared__ __bf16 KhL[2][4096];     // 32 rows x 128 bf16, linear, dbuf
    __shared__ __bf16 KlL[2][4096];
    __shared__ __bf16 VtL[4096];        // 128 rows x 32 bf16, SINGLE buffer
    __shared__ __bf16 Pt[4][16 * PTSTRIDE];

    const float* Fh  = F  + h * (S_LEN + 1);
    const float* ugh = ug + h * S_LEN;
    const float scale = 0.088388347648318447f; // 1/sqrt(128)

    const int krow0 = tid >> 4;
    const int krow1 = 16 + krow0;
    const int kchk  = (tid & 15) ^ (krow0 & 15);
    const int vrow0 = tid >> 2;
    const int vrow1 = 64 + vrow0;
    const int vchk  = (tid & 3) ^ ((vrow0 ^ (vrow0 >> 2)) & 3);
    const int ldsw  = w * 512;

#define STAGE_K(B, TB) do {                                                   \
    const __bf16* kb_ = Khg + (size_t)(TB) * EMB + h * DH;                    \
    const __bf16* lb_ = Klg + (size_t)(TB) * EMB + h * DH;                    \
    gload16(kb_ + (size_t)krow0 * EMB + kchk * 8, &KhL[B][ldsw]);             \
    gload16(kb_ + (size_t)krow1 * EMB + kchk * 8, &KhL[B][2048 + ldsw]);      \
    gload16(lb_ + (size_t)krow0 * EMB + kchk * 8, &KlL[B][ldsw]);             \
    gload16(lb_ + (size_t)krow1 * EMB + kchk * 8, &KlL[B][2048 + ldsw]);      \
} while (0)
#define STAGE_V(TB) do {                                                      \
    const __bf16* vg_ = Vtg + (size_t)(h * DH) * S_LEN + (TB);                \
    gload16(vg_ + (size_t)vrow0 * S_LEN + vchk * 8, &VtL[ldsw]);              \
    gload16(vg_ + (size_t)vrow1 * S_LEN + vchk * 8, &VtL[2048 + ldsw]);       \
} while (0)

    for (int pair = 0; pair < 2; ++pair) {
        const int qt = (pair == 0) ? xx : 31 - xx;
        const int qb = qt * BM;
        const int nj = 2 * qt + 2;
        const int j0 = (z * nj) / NSPLIT, j1 = ((z + 1) * nj) / NSPLIT;
        const int qbw = qb + w * 16;
        const int SBLK = (qb >> 5) + (w >> 1);   // uniform per wave

        float fq[4], upm[4];
        int sglob[4];
        #pragma unroll
        for (int r = 0; r < 4; ++r) {
            int s = qbw + quad * 4 + r;
            sglob[r] = s;
            fq[r]  = Fh[s + 1];
            upm[r] = upmaxg[h * S_LEN + s];
        }

        bf16x8 qh[4], ql[4];
        {
            const size_t qrow = (size_t)(qbw + l15) * EMB + h * DH + quad * 8;
            #pragma unroll
            for (int kk = 0; kk < 4; ++kk) {
                qh[kk] = *(const bf16x8*)(Qhg + qrow + kk * 32);
                ql[kk] = *(const bf16x8*)(Qlg + qrow + kk * 32);
            }
        }
        #pragma unroll
        for (int kk = 0; kk < 4; ++kk)
            asm volatile("" : "+v"(qh[kk]), "+v"(ql[kk]));

        float m_r[4] = {-1e30f, -1e30f, -1e30f, -1e30f};
        float l_r[4] = {0.f, 0.f, 0.f, 0.f};
        f32x4 Oacc[8] = {{0,0,0,0},{0,0,0,0},{0,0,0,0},{0,0,0,0},
                         {0,0,0,0},{0,0,0,0},{0,0,0,0},{0,0,0,0}};

        float pu0 = 0.f, pu1 = 0.f, pum = 0.f;
        int buf = 0;
        if (j0 < j1) {
            STAGE_K(0, j0 * BN);
            pu0 = ugh[j0 * BN + l15];
            pu1 = ugh[j0 * BN + 16 + l15];
            pum = umaxg[h * 64 + j0];
            __syncthreads();   // vmcnt(0): first K tile landed
        }

        for (int j = j0; j < j1; ++j) {
            const int tb = j * BN;
            STAGE_V(tb);                       // V[j] -> single buffer
            if (j + 1 < j1) STAGE_K(buf ^ 1, tb + BN);
            const float ut0 = pu0, ut1 = pu1, umj = pum;
            if (j + 1 < j1) {
                pu0 = ugh[tb + BN + l15];
                pu1 = ugh[tb + BN + 16 + l15];
                pum = umaxg[h * 64 + (j + 1)];
            }
            if (j <= SBLK) {   // wave-uniform: skip fully-masked tiles
                f32x4 S0 = {0,0,0,0}, S1 = {0,0,0,0};
                #pragma unroll
                for (int kk = 0; kk < 4; ++kk) {
                    const int kpos = (((kk << 2) | quad) ^ l15) * 8;
                    bf16x8 bh0 = *(const bf16x8*)&KhL[buf][l15 * 128 + kpos];
                    bf16x8 bl0 = *(const bf16x8*)&KlL[buf][l15 * 128 + kpos];
                    S0 = __builtin_amdgcn_mfma_f32_16x16x32_bf16(qh[kk], bh0, S0, 0, 0, 0);
                    S0 = __builtin_amdgcn_mfma_f32_16x16x32_bf16(qh[kk], bl0, S0, 0, 0, 0);
                    S0 = __builtin_amdgcn_mfma_f32_16x16x32_bf16(ql[kk], bh0, S0, 0, 0, 0);
                    bf16x8 bh1 = *(const bf16x8*)&KhL[buf][(16 + l15) * 128 + kpos];
                    bf16x8 bl1 = *(const bf16x8*)&KlL[buf][(16 + l15) * 128 + kpos];
                    S1 = __builtin_amdgcn_mfma_f32_16x16x32_bf16(qh[kk], bh1, S1, 0, 0, 0);
                    S1 = __builtin_amdgcn_mfma_f32_16x16x32_bf16(qh[kk], bl1, S1, 0, 0, 0);
                    S1 = __builtin_amdgcn_mfma_f32_16x16x32_bf16(ql[kk], bh1, S1, 0, 0, 0);
                }
                const int t0 = tb + l15, t1 = tb + 16 + l15;
                #pragma unroll
                for (int r = 0; r < 4; ++r) {
                    float mt = (j < SBLK) ? (fq[r] + umj) : (fq[r] + upm[r]);
                    float mn = fmaxf(m_r[r], mt);
                    float alpha = __expf(m_r[r] - mn);
                    m_r[r] = mn;
                    #pragma unroll
                    for (int nt = 0; nt < 8; ++nt) Oacc[nt][r] *= alpha;
                    float p0 = __expf(fq[r] + ut0 - mn) * S0[r] * scale;
                    float p1 = __expf(fq[r] + ut1 - mn) * S1[r] * scale;
                    if (j == SBLK) {
                        if (t0 > sglob[r]) p0 = 0.f;
                        if (t1 > sglob[r]) p1 = 0.f;
                    }
                    l_r[r] = l_r[r] * alpha + (p0 + p1);  // per-lane partial
                    const int prow = (quad * 4 + r) * PTSTRIDE;
                    Pt[w][prow + l15]      = (__bf16)p0;
                    Pt[w][prow + 16 + l15] = (__bf16)p1;
                }
            }
            __syncthreads();   // vmcnt(0): V[j] (and K[j+1]) landed, block-wide
            if (j <= SBLK) {
                bf16x8 pa = *(const bf16x8*)&Pt[w][l15 * PTSTRIDE + quad * 8];
                #pragma unroll
                for (int nt = 0; nt < 8; ++nt) {
                    const int vrow = nt * 16 + l15;
                    const int vpos = (quad ^ ((vrow ^ (vrow >> 2)) & 3)) * 8;
                    bf16x8 vv = *(const bf16x8*)&VtL[vrow * 32 + vpos];
                    Oacc[nt] = __builtin_amdgcn_mfma_f32_16x16x32_bf16(pa, vv, Oacc[nt], 0, 0, 0);
                }
            }
            __syncthreads();   // all PV reads of V[j] done before next overwrite
            buf ^= 1;
        }
        __bf16* Oz = Opart + (size_t)z * S_LEN * EMB;
        #pragma unroll
        for (int nt = 0; nt < 8; ++nt) {
            #pragma unroll
            for (int r = 0; r < 4; ++r) {
                Oz[(size_t)sglob[r] * EMB + h * DH + nt * 16 + l15] = (__bf16)Oacc[nt][r];
            }
        }
        #pragma unroll
        for (int r = 0; r < 4; ++r) {
            float x = l_r[r];
            #pragma unroll
            for (int o = 1; o < 16; o <<= 1) x += __shfl_xor(x, o);
            l_r[r] = x;
        }
        if (l15 == 0) {
            #pragma unroll
            for (int r = 0; r < 4; ++r) {
                msplit[(z * NHEAD + h) * S_LEN + sglob[r]] = m_r[r];
                lsplit[(z * NHEAD + h) * S_LEN + sglob[r]] = l_r[r];
            }
        }
    }
#undef STAGE_K
#undef STAGE_V
}

// ---------------------------------------------------------------------------
// Kernel 4: combine split-K partials + normalize + LN (R20 form, NSPLIT=4,
// es!=0 skip).
// ---------------------------------------------------------------------------
__global__ __launch_bounds__(256) void combine_ln_kernel(
    const __bf16* __restrict__ Opart, const float* __restrict__ msplit,
    const float* __restrict__ lsplit, const float* __restrict__ lnw,
    float* __restrict__ out)
{
    const int tid = threadIdx.x;
    const int r  = tid >> 7;          // row within block (0/1)
    const int wr = (tid >> 6) & 1;    // wave within row
    const int c0 = (tid & 127) * 8;   // 8 contiguous cols per thread
    const int hh = c0 >> 7;
    const int s  = blockIdx.x * 2 + r;
    __shared__ float redsum[2][2], redvar[2][2];

    float m = -1e30f, es[NSPLIT], l = 0.f;
    #pragma unroll
    for (int zz = 0; zz < NSPLIT; ++zz)
        m = fmaxf(m, msplit[(zz * NHEAD + hh) * S_LEN + s]);
    #pragma unroll
    for (int zz = 0; zz < NSPLIT; ++zz) {
        es[zz] = __expf(msplit[(zz * NHEAD + hh) * S_LEN + s] - m);
        l += es[zz] * lsplit[(zz * NHEAD + hh) * S_LEN + s];
    }
    const float rn = 1.f / (fmaxf(fabsf(l), __expf(-m)) + 1e-6f);

    const size_t SE = (size_t)S_LEN * EMB;
    float x[8] = {0,0,0,0,0,0,0,0};
    #pragma unroll
    for (int zz = 0; zz < NSPLIT; ++zz) {
        if (es[zz] != 0.f) {
            bf16x8 o = *(const bf16x8*)(Opart + zz * SE + (size_t)s * EMB + c0);
            #pragma unroll
            for (int e = 0; e < 8; ++e) x[e] += es[zz] * (float)o[e];
        }
    }
    float sum = 0.f;
    #pragma unroll
    for (int e = 0; e < 8; ++e) { x[e] *= rn; sum += x[e]; }
    for (int o = 32; o > 0; o >>= 1) sum += __shfl_down(sum, o, 64);
    if ((tid & 63) == 0) redsum[r][wr] = sum;
    __syncthreads();
    sum = redsum[r][0] + redsum[r][1];
    const float mu = sum * (1.f / EMB);
    float vs = 0.f;
    #pragma unroll
    for (int e = 0; e < 8; ++e) { float d = x[e] - mu; vs += d * d; }
    for (int o = 32; o > 0; o >>= 1) vs += __shfl_down(vs, o, 64);
    if ((tid & 63) == 0) redvar[r][wr] = vs;
    __syncthreads();
    vs = redvar[r][0] + redvar[r][1];
    const float rstd = rsqrtf(vs * (1.f / EMB) + 1e-5f);
    const float4 w0 = *(const float4*)(lnw + c0);
    const float4 w1 = *(const float4*)(lnw + c0 + 4);
    float4 o0, o1;
    o0.x = (x[0]-mu)*rstd*(1.f+w0.x); o0.y = (x[1]-mu)*rstd*(1.f+w0.y);
    o0.z = (x[2]-mu)*rstd*(1.f+w0.z); o0.w = (x[3]-mu)*rstd*(1.f+w0.w);
    o1.x = (x[4]-mu)*rstd*(1.f+w1.x); o1.y = (x[5]-mu)*rstd*(1.f+w1.y);
    o1.z = (x[6]-mu)*rstd*(1.f+w1.z); o1.w = (x[7]-mu)*rstd*(1.f+w1.w);
    *(float4*)(out + (size_t)s * EMB + c0)     = o0;
    *(float4*)(out + (size_t)s * EMB + c0 + 4) = o1;
}

// ---------------------------------------------------------------------------
extern "C" void kernel_launch(void* const* d_in, const int* in_sizes, int n_in,
                              void* d_out, int out_size, void* d_ws, size_t ws_size,
                              hipStream_t stream)
{
    const float* q   = (const float*)d_in[0];
    const float* k   = (const float*)d_in[1];
    const float* v   = (const float*)d_in[2];
    const float* Wi  = (const float*)d_in[3];
    const float* bi  = (const float*)d_in[4];
    const float* Wf  = (const float*)d_in[5];
    const float* bf  = (const float*)d_in[6];
    const float* lnw = (const float*)d_in[7];
    float* out = (float*)d_out;

    // workspace layout (~37.7 MB; 38.6 proven safe, 47.3 overflowed in R9):
    float* ws = (float*)d_ws;
    float* gpart = ws;                              // KSPLIT*16*S (1 MB)
    float* F     = gpart + KSPLIT * 16 * S_LEN;     // NH*(S+1)
    float* ugw   = F + NHEAD * (S_LEN + 1);         // NH*S
    float* umaxw = ugw + NHEAD * S_LEN;             // NH*64
    float* upmaxw= umaxw + NHEAD * 64;              // NH*S
    __bf16* Qh = (__bf16*)(upmaxw + NHEAD * S_LEN);
    const size_t SEb = (size_t)S_LEN * EMB;
    __bf16* Ql  = Qh + SEb;
    __bf16* Kh  = Ql + SEb;
    __bf16* Kl  = Kh + SEb;
    __bf16* Vtg = Kl + SEb;
    __bf16* Opart = Vtg + SEb;                      // NSPLIT*S*EMB bf16 (16 MB)
    float* msplit = (float*)(Opart + (size_t)NSPLIT * SEb);
    float* lsplit = msplit + NSPLIT * NHEAD * S_LEN;

    gates_gemm_cvt_trans_kernel<<<NGEMM + S_LEN + 2048, 256, 0, stream>>>(
        q, k, v, Wi, Wf, Qh, Ql, Kh, Kl, Vtg, gpart);
    cumsum_aux_kernel<<<NHEAD, 256, 0, stream>>>(
        gpart, bi, bf, F, ugw, umaxw, upmaxw);
    mlstm_mfma<<<16 * NHEAD * NSPLIT, 256, 0, stream>>>(
        Qh, Ql, Kh, Kl, Vtg, ugw, umaxw, upmaxw, F, Opart, msplit, lsplit);
    combine_ln_kernel<<<S_LEN / 2, 256, 0, stream>>>(Opart, msplit, lsplit, lnw, out);
}